// Round 1
// baseline (2999.696 us; speedup 1.0000x reference)
//
#include <hip/hip_runtime.h>
#include <math.h>

typedef unsigned int u32;
typedef unsigned long long u64;

#define HH 128
#define WW 128
#define NPIX (128*128)
#define CIN 1024
#define COC 512
#define NANCH (NPIX*6)
#define KPRE 6000
#define KPOST 300
#define SORT_CAP 16384
#define RW 96            /* u64 words per bitmap row */
#define NMS_T 0.7f

#define OUT_PROB 1500
#define OUT_BBOX (1500 + 98304)

/* ---------------- ws layout (bytes) ---------------- */
#define WS_CONV1 ((size_t)0)                     /* 512*16384*4 = 33554432 */
#define WS_BOXES ((size_t)33554432)              /* 98304*16    = 1572864  */
#define WS_SCORE (WS_BOXES + 1572864)            /* 98304*4     = 393216   */
#define WS_KEYS  (WS_SCORE + 393216)             /* 16384*8     = 131072   */
#define WS_TB    (WS_KEYS + 131072)              /* 6144*16     = 98304    */
#define WS_AREA  (WS_TB + 98304)                 /* 6144*4      = 24576    */
#define WS_SUP   (WS_AREA + 24576)               /* 6144*96*8   = 4718592  */
#define WS_HIST  (WS_SUP + 4718592)              /* 65536*4     = 262144   */
#define WS_CTRL  (WS_HIST + 262144)              /* 64*4 -> pad 256        */
#define WS_KEEP  (WS_CTRL + 256)                 /* 304*4 -> pad 1280      */
#define WS_SKEYS (WS_KEEP + 1280)                /* 6144*8      = 49152    */
/* total ~40.8 MB */

/* ---------------- init: zero hist/ctrl, keep=-1, keys=MAX ---------------- */
__global__ void k_init(u32* __restrict__ hist, u32* __restrict__ ctrl,
                       int* __restrict__ keep, u64* __restrict__ keys) {
    int t = blockIdx.x * blockDim.x + threadIdx.x;
    if (t < 65536) hist[t] = 0u;
    if (t < 64)    ctrl[t] = 0u;
    if (t < 304)   keep[t] = -1;
    if (t < SORT_CAP) keys[t] = ~0ULL;
}

/* ---------------- conv 3x3, 1024->512, pad 1, relu ----------------
   grid (128 rows, 8 oc-tiles), 256 threads. Block: 64 oc x full 128-px row.
   Thread: 4 oc x 8 px. K staged in chunks of 8 input channels. */
__global__ __launch_bounds__(256) void k_conv3(const float* __restrict__ in,
                                               const float* __restrict__ w,
                                               const float* __restrict__ bias,
                                               float* __restrict__ out) {
    const int y   = blockIdx.x;
    const int oc0 = blockIdx.y * 64;
    const int tid = threadIdx.x;
    const int og  = tid >> 4;   /* 0..15 -> ocs og*4..+3 */
    const int pg  = tid & 15;   /* 0..15 -> px pg*8..+7  */

    __shared__ __align__(16) float Xl[8][3][132];   /* [c'][dy][x+1], 12.7KB */
    __shared__ __align__(16) float Wl[72][68];      /* [c'*9+r][oc], 19.6KB  */

    float acc[4][8];
#pragma unroll
    for (int o = 0; o < 4; ++o)
#pragma unroll
        for (int j = 0; j < 8; ++j) acc[o][j] = 0.f;

    for (int cc = 0; cc < 128; ++cc) {
        const int c0 = cc * 8;
        /* stage input 8c x 3dy x 130 cols (halo zeros at col 0 and 129) */
        for (int u = tid; u < 8 * 3 * 132; u += 256) {
            int rowi = u / 132;
            int col  = u - rowi * 132;
            int cp = rowi / 3, dy = rowi - cp * 3;
            int yy = y + dy - 1;
            int xx = col - 1;
            float v = 0.f;
            if (yy >= 0 && yy < HH && xx >= 0 && xx < WW && col < 130)
                v = in[(size_t)(c0 + cp) * NPIX + yy * WW + xx];
            Xl[cp][dy][col] = v;
        }
        /* stage weights transposed: Wl[c'*9+r][oc] */
        for (int u = tid; u < 64 * 72 / 4; u += 256) {
            int oc  = (u * 4) / 72;
            int col = (u * 4) - oc * 72;
            const float4 wv = *(const float4*)(w + (size_t)(oc0 + oc) * 9216 + (size_t)cc * 72 + col);
            Wl[col + 0][oc] = wv.x;
            Wl[col + 1][oc] = wv.y;
            Wl[col + 2][oc] = wv.z;
            Wl[col + 3][oc] = wv.w;
        }
        __syncthreads();

        for (int cp = 0; cp < 8; ++cp) {
            float v[3][10];
#pragma unroll
            for (int dy = 0; dy < 3; ++dy) {
                const float* xp = &Xl[cp][dy][pg * 8];
                float4 pa = *(const float4*)xp;
                float4 pb = *(const float4*)(xp + 4);
                v[dy][0] = pa.x; v[dy][1] = pa.y; v[dy][2] = pa.z; v[dy][3] = pa.w;
                v[dy][4] = pb.x; v[dy][5] = pb.y; v[dy][6] = pb.z; v[dy][7] = pb.w;
                v[dy][8] = xp[8]; v[dy][9] = xp[9];
            }
#pragma unroll
            for (int r = 0; r < 9; ++r) {
                const int dy = r / 3, dx = r % 3;
                const float4 wv4 = *(const float4*)&Wl[cp * 9 + r][og * 4];
#pragma unroll
                for (int j = 0; j < 8; ++j) {
                    const float xv = v[dy][j + dx];
                    acc[0][j] = fmaf(wv4.x, xv, acc[0][j]);
                    acc[1][j] = fmaf(wv4.y, xv, acc[1][j]);
                    acc[2][j] = fmaf(wv4.z, xv, acc[2][j]);
                    acc[3][j] = fmaf(wv4.w, xv, acc[3][j]);
                }
            }
        }
        __syncthreads();
    }
#pragma unroll
    for (int o = 0; o < 4; ++o) {
        const int oc = oc0 + og * 4 + o;
        const float b = bias[oc];
#pragma unroll
        for (int j = 0; j < 8; ++j) {
            float vv = acc[o][j] + b;
            out[(size_t)oc * NPIX + y * WW + pg * 8 + j] = vv > 0.f ? vv : 0.f;
        }
    }
}

/* ---------------- fused 1x1 convs (cls 6 + bbox 24) + pair softmax ----------------
   grid 256 blocks x 256 thr; block: 32 oc (30 real) x 64 px. Thread: 2 oc x 4 px. */
__global__ __launch_bounds__(256) void k_conv1(const float* __restrict__ conv1,
                                               const float* __restrict__ wcls,
                                               const float* __restrict__ bcls,
                                               const float* __restrict__ wbox,
                                               const float* __restrict__ bboxb,
                                               float* __restrict__ out) {
    const int tid = threadIdx.x;
    const int og = tid >> 4, pg = tid & 15;
    const int px0 = blockIdx.x * 64;
    __shared__ __align__(16) float Wl[32][32];
    __shared__ __align__(16) float Xl[32][64];
    __shared__ float Sc[6][64];

    float a0[4] = {0, 0, 0, 0}, a1[4] = {0, 0, 0, 0};

    for (int cc = 0; cc < 16; ++cc) {
        /* stage weights chunk: rows 0..5 = cls, 6..29 = bbox, 30/31 = 0 */
        {
            int u = tid; /* 256 float4 = 32x32 */
            int row = (u * 4) >> 5;
            int col = (u * 4) & 31;
            float4 v;
            if (row < 6)       v = *(const float4*)(wcls + row * 512 + cc * 32 + col);
            else if (row < 30) v = *(const float4*)(wbox + (row - 6) * 512 + cc * 32 + col);
            else               v = make_float4(0.f, 0.f, 0.f, 0.f);
            *(float4*)&Wl[row][col] = v;
        }
        /* stage conv1 tile 32c x 64px */
        for (int u = tid; u < 512; u += 256) {
            int row = (u * 4) >> 6, col = (u * 4) & 63;
            *(float4*)&Xl[row][col] =
                *(const float4*)(conv1 + (size_t)(cc * 32 + row) * NPIX + px0 + col);
        }
        __syncthreads();
#pragma unroll
        for (int cp = 0; cp < 32; ++cp) {
            const float4 x = *(const float4*)&Xl[cp][pg * 4];
            const float w0 = Wl[og][cp];
            const float w1 = Wl[og + 16][cp];
            a0[0] = fmaf(w0, x.x, a0[0]); a0[1] = fmaf(w0, x.y, a0[1]);
            a0[2] = fmaf(w0, x.z, a0[2]); a0[3] = fmaf(w0, x.w, a0[3]);
            a1[0] = fmaf(w1, x.x, a1[0]); a1[1] = fmaf(w1, x.y, a1[1]);
            a1[2] = fmaf(w1, x.z, a1[2]); a1[3] = fmaf(w1, x.w, a1[3]);
        }
        __syncthreads();
    }
    const int pxb = px0 + pg * 4;
    if (og < 6) {
        const float bc = bcls[og];
#pragma unroll
        for (int kk = 0; kk < 4; ++kk) Sc[og][pg * 4 + kk] = a0[kk] + bc;
    } else {
        const float bb = bboxb[og - 6];
#pragma unroll
        for (int kk = 0; kk < 4; ++kk)
            out[OUT_BBOX + (size_t)(og - 6) * NPIX + pxb + kk] = a0[kk] + bb;
    }
    if (og + 16 < 30) {
        const float bb = bboxb[og + 10];
#pragma unroll
        for (int kk = 0; kk < 4; ++kk)
            out[OUT_BBOX + (size_t)(og + 10) * NPIX + pxb + kk] = a1[kk] + bb;
    }
    __syncthreads();
    if (og < 6) {
        const int pa = og < 3 ? og + 3 : og - 3;
#pragma unroll
        for (int kk = 0; kk < 4; ++kk) {
            const float s = Sc[og][pg * 4 + kk], sp = Sc[pa][pg * 4 + kk];
            out[OUT_PROB + (size_t)og * NPIX + pxb + kk] = 1.0f / (1.0f + expf(sp - s));
        }
    }
}

/* ---------------- anchor decode + clip ---------------- */
__global__ void k_decode(const float* __restrict__ out, const float* __restrict__ meta,
                         float4* __restrict__ boxes, float* __restrict__ scores) {
#pragma clang fp contract(off)
    int t = blockIdx.x * blockDim.x + threadIdx.x;
    if (t >= NANCH) return;
    int a = t >> 14;
    int pix = t & 16383;
    int yc = pix >> 7, xc = pix & 127;
    int n = pix * 6 + a;
    float sc = out[OUT_PROB + (size_t)a * NPIX + pix];
    float d0 = out[OUT_BBOX + (size_t)(a * 4 + 0) * NPIX + pix];
    float d1 = out[OUT_BBOX + (size_t)(a * 4 + 1) * NPIX + pix];
    float d2 = out[OUT_BBOX + (size_t)(a * 4 + 2) * NPIX + pix];
    float d3 = out[OUT_BBOX + (size_t)(a * 4 + 3) * NPIX + pix];
    const float dims = (float)(16 << a);
    const float cxa = (xc + 0.5f) * 16.f;
    const float cya = (yc + 0.5f) * 16.f;
    float pcx = d0 * dims + cxa;
    float pcy = d1 * dims + cya;
    float pw  = expf(d2) * dims;
    float ph  = expf(d3) * dims;
    float imh = meta[0], imw = meta[1];
    float x1 = fminf(fmaxf(pcx - 0.5f * pw, 0.f), imw);
    float y1 = fminf(fmaxf(pcy - 0.5f * ph, 0.f), imh);
    float x2 = fminf(fmaxf(pcx + 0.5f * pw, 0.f), imw);
    float y2 = fminf(fmaxf(pcy + 0.5f * ph, 0.f), imh);
    boxes[n] = make_float4(x1, y1, x2, y2);
    scores[n] = sc;
}

/* ---------------- histogram on top-16 bits of score ---------------- */
__global__ void k_hist(const float* __restrict__ scores, u32* __restrict__ hist) {
    int t = blockIdx.x * blockDim.x + threadIdx.x;
    if (t >= NANCH) return;
    u32 b = __float_as_uint(scores[t]) >> 16;
    atomicAdd(&hist[b], 1u);
}

/* ---------------- find threshold bin (6000th largest) ---------------- */
__global__ void k_select(const u32* __restrict__ hist, u32* __restrict__ ctrl) {
    __shared__ u32 S[256];
    __shared__ u32 U[256];
    const int tid = threadIdx.x;
    u32 s = 0;
    for (int i = 0; i < 256; ++i) s += hist[tid * 256 + i];
    S[tid] = s;
    __syncthreads();
    if (tid == 0) {
        u32 acc = 0;
        for (int t = 255; t >= 0; --t) { U[t] = acc; acc += S[t]; }
    }
    __syncthreads();
    if (U[tid] < KPRE && U[tid] + S[tid] >= KPRE) {
        u32 acc = U[tid];
        for (int b = tid * 256 + 255; b >= tid * 256; --b) {
            u32 h = hist[b];
            if (acc + h >= KPRE) { ctrl[1] = (u32)b; ctrl[2] = acc; break; }
            acc += h;
        }
    }
}

/* ---------------- compact candidates (bin >= threshold bin) ---------------- */
__global__ void k_compact(const float* __restrict__ scores, u32* __restrict__ ctrl,
                          u64* __restrict__ keys) {
    int t = blockIdx.x * blockDim.x + threadIdx.x;
    if (t >= NANCH) return;
    u32 bits = __float_as_uint(scores[t]);
    if ((bits >> 16) >= ctrl[1]) {
        u32 pos = atomicAdd(&ctrl[0], 1u);
        if (pos < SORT_CAP) keys[pos] = ((u64)(~bits) << 32) | (u32)t;
    }
}

/* ---------------- bitonic sort of 8192-key chunk in LDS ---------------- */
__global__ __launch_bounds__(1024) void k_sort_local(u64* __restrict__ keys) {
    __shared__ u64 lds[8192];
    const int tid = threadIdx.x;
    u64* g = keys + blockIdx.x * 8192;
    for (int u = tid; u < 8192; u += 1024) lds[u] = g[u];
    __syncthreads();
    for (int k = 2; k <= 8192; k <<= 1) {
        for (int j = k >> 1; j > 0; j >>= 1) {
            for (int u = tid; u < 4096; u += 1024) {
                int i = ((u & ~(j - 1)) << 1) | (u & (j - 1));
                int l = i | j;
                bool up = (i & k) == 0;
                u64 x = lds[i], y2 = lds[l];
                if ((x > y2) == up) { lds[i] = y2; lds[l] = x; }
            }
            __syncthreads();
        }
    }
    for (int u = tid; u < 8192; u += 1024) g[u] = lds[u];
}

/* ---------------- merge-path: first 6000 of two sorted 8192 runs ---------------- */
__global__ void k_merge(const u64* __restrict__ keys, u64* __restrict__ skeys) {
    int i = blockIdx.x * blockDim.x + threadIdx.x;
    if (i >= KPRE) return;
    const u64* A = keys;
    const u64* B = keys + 8192;
    int lo = i > 8192 ? i - 8192 : 0;
    int hi = i < 8192 ? i : 8192;
    while (lo < hi) {
        int a = (lo + hi) >> 1;
        if (A[a] < B[i - a - 1]) lo = a + 1; else hi = a;
    }
    int a = lo, b = i - lo;
    u64 va = (a < 8192) ? A[a] : ~0ULL;
    u64 vb = (b < 8192) ? B[b] : ~0ULL;
    skeys[i] = va < vb ? va : vb;
}

/* ---------------- gather top boxes + areas ---------------- */
__global__ void k_gather(const u64* __restrict__ skeys, const float4* __restrict__ boxes,
                         float4* __restrict__ tb, float* __restrict__ areas) {
#pragma clang fp contract(off)
    int i = blockIdx.x * blockDim.x + threadIdx.x;
    if (i >= KPRE) return;
    u32 n = (u32)(skeys[i] & 0xFFFFFFFFULL);
    float4 b = boxes[n];
    tb[i] = b;
    areas[i] = fmaxf(b.z - b.x, 0.f) * fmaxf(b.w - b.y, 0.f);
}

/* ---------------- suppression bitmap: row i = boxes suppressed by i ---------------- */
__global__ __launch_bounds__(256) void k_bitmap(const float4* __restrict__ tb,
                                                const float* __restrict__ areas,
                                                u64* __restrict__ suppr) {
#pragma clang fp contract(off)
    const int i = blockIdx.x;
    const int lane = threadIdx.x & 63;
    const int wv = threadIdx.x >> 6;
    const float4 bi = tb[i];
    const float ai = areas[i];
    for (int Wd = wv; Wd < RW; Wd += 4) {
        int j = Wd * 64 + lane;
        bool sup = false;
        if (j < KPRE) {
            float4 bj = tb[j];
            float iw = fmaxf(fminf(bi.z, bj.z) - fmaxf(bi.x, bj.x), 0.f);
            float ih = fmaxf(fminf(bi.w, bj.w) - fmaxf(bi.y, bj.y), 0.f);
            float inter = iw * ih;
            float denom = ((areas[j] + ai) - inter) + 1e-9f;
            sup = (inter / denom) > NMS_T;
        }
        u64 m = __ballot(sup);
        if (lane == 0) suppr[(size_t)i * RW + Wd] = m;
    }
}

/* ---------------- greedy scan over bitmap (== reference NMS) ---------------- */
__global__ void k_scan(const u64* __restrict__ suppr, int* __restrict__ keep) {
    const int lane = threadIdx.x; /* 64 threads */
    u64 a0 = (lane < 93) ? ~0ULL : (lane == 93 ? ((1ULL << 48) - 1) : 0ULL);
    const int w1 = lane + 64;
    u64 a1 = (w1 < 93) ? ~0ULL : (w1 == 93 ? ((1ULL << 48) - 1) : 0ULL);
    int kept = 0;
    int i = 0;
    while (kept < KPOST) {
        int wi = i >> 6;
        if (wi >= 94) break;
        u64 wvv = (wi < 64) ? __shfl(a0, wi) : __shfl(a1, wi - 64);
        wvv &= (~0ULL) << (i & 63);
        if (wvv == 0ULL) { i = (wi + 1) << 6; continue; }
        int b = __ffsll((long long)wvv) - 1;
        i = (wi << 6) + b;
        if (lane == 0) keep[kept] = i;
        kept++;
        const u64* row = suppr + (size_t)i * RW;
        u64 s0 = row[lane];
        u64 s1 = (lane + 64 < RW) ? row[lane + 64] : 0ULL;
        a0 &= ~s0;
        a1 &= ~s1;
        i++;
    }
}

/* ---------------- write rois ---------------- */
__global__ void k_rois(const int* __restrict__ keep, const float4* __restrict__ tb,
                       float* __restrict__ out) {
    int r = blockIdx.x * blockDim.x + threadIdx.x;
    if (r >= KPOST) return;
    int k = keep[r];
    float4 b = make_float4(0.f, 0.f, 0.f, 0.f);
    if (k >= 0) b = tb[k];
    out[r * 5 + 0] = 0.f;
    out[r * 5 + 1] = b.x;
    out[r * 5 + 2] = b.y;
    out[r * 5 + 3] = b.z;
    out[r * 5 + 4] = b.w;
}

extern "C" void kernel_launch(void* const* d_in, const int* in_sizes, int n_in,
                              void* d_out, int out_size, void* d_ws, size_t ws_size,
                              hipStream_t stream) {
    (void)in_sizes; (void)n_in; (void)out_size; (void)ws_size;
    const float* x     = (const float*)d_in[0];
    const float* meta  = (const float*)d_in[1];
    const float* wc3   = (const float*)d_in[3];
    const float* bc3   = (const float*)d_in[4];
    const float* wcls  = (const float*)d_in[5];
    const float* bcls  = (const float*)d_in[6];
    const float* wbox  = (const float*)d_in[7];
    const float* bboxb = (const float*)d_in[8];
    float* out = (float*)d_out;
    char* ws = (char*)d_ws;

    float*  conv1  = (float*)(ws + WS_CONV1);
    float4* boxes  = (float4*)(ws + WS_BOXES);
    float*  scores = (float*)(ws + WS_SCORE);
    u64*    keys   = (u64*)(ws + WS_KEYS);
    float4* tb     = (float4*)(ws + WS_TB);
    float*  areas  = (float*)(ws + WS_AREA);
    u64*    suppr  = (u64*)(ws + WS_SUP);
    u32*    hist   = (u32*)(ws + WS_HIST);
    u32*    ctrl   = (u32*)(ws + WS_CTRL);
    int*    keep   = (int*)(ws + WS_KEEP);
    u64*    skeys  = (u64*)(ws + WS_SKEYS);

    k_init<<<256, 256, 0, stream>>>(hist, ctrl, keep, keys);
    k_conv3<<<dim3(128, 8), 256, 0, stream>>>(x, wc3, bc3, conv1);
    k_conv1<<<256, 256, 0, stream>>>(conv1, wcls, bcls, wbox, bboxb, out);
    k_decode<<<384, 256, 0, stream>>>(out, meta, boxes, scores);
    k_hist<<<384, 256, 0, stream>>>(scores, hist);
    k_select<<<1, 256, 0, stream>>>(hist, ctrl);
    k_compact<<<384, 256, 0, stream>>>(scores, ctrl, keys);
    k_sort_local<<<2, 1024, 0, stream>>>(keys);
    k_merge<<<24, 256, 0, stream>>>(keys, skeys);
    k_gather<<<24, 256, 0, stream>>>(skeys, boxes, tb, areas);
    k_bitmap<<<6000, 256, 0, stream>>>(tb, areas, suppr);
    k_scan<<<1, 64, 0, stream>>>(suppr, keep);
    k_rois<<<2, 256, 0, stream>>>(keep, tb, out);
}

// Round 2
// 2499.408 us; speedup vs baseline: 1.2002x; 1.2002x over previous
//
#include <hip/hip_runtime.h>
#include <math.h>

typedef unsigned int u32;
typedef unsigned long long u64;

#define HH 128
#define WW 128
#define NPIX (128*128)
#define NANCH (NPIX*6)
#define KPRE 6000
#define KPOST 300
#define SORT_CAP 16384
#define RW 96            /* u64 words per bitmap row */
#define NMS_T 0.7f

#define OUT_PROB 1500
#define OUT_BBOX (1500 + 98304)

/* ---------------- ws layout (bytes) ----------------
   conv1: 0 .. 33.5MB (live during conv3+conv1)
   wt   : 33.5MB .. 52.4MB (live only during conv3)
   post-conv3 buffers alias the wt region (k_init runs AFTER conv3). */
#define WS_CONV1 ((size_t)0)                     /* 512*16384*4 = 33554432 */
#define WS_WT    ((size_t)33554432)              /* 9216*512*4  = 18874368 */
#define WS_BOXES ((size_t)33554432)              /* 98304*16    = 1572864  */
#define WS_SCORE (WS_BOXES + 1572864)            /* 98304*4     = 393216   */
#define WS_KEYS  (WS_SCORE + 393216)             /* 16384*8     = 131072   */
#define WS_TB    (WS_KEYS + 131072)              /* 6144*16     = 98304    */
#define WS_AREA  (WS_TB + 98304)                 /* 6144*4      = 24576    */
#define WS_SUP   (WS_AREA + 24576)               /* 6144*96*8   = 4718592  */
#define WS_HIST  (WS_SUP + 4718592)              /* 65536*4     = 262144   */
#define WS_CTRL  (WS_HIST + 262144)              /* pad 256                */
#define WS_KEEP  (WS_CTRL + 256)                 /* pad 1280               */
#define WS_SKEYS (WS_KEEP + 1280)                /* 6144*8      = 49152    */
/* total needed = 33554432 + 18874368 = 52428800 bytes */

/* bank swizzle: block b -> b ^ ((b>>4)&1); keeps 4-word blocks intact */
__device__ __forceinline__ int swb(int b) { return b ^ ((b >> 4) & 1); }

/* ---------------- init (runs AFTER conv3; aliases wt region) ---------------- */
__global__ void k_init(u32* __restrict__ hist, u32* __restrict__ ctrl,
                       int* __restrict__ keep, u64* __restrict__ keys) {
    int t = blockIdx.x * blockDim.x + threadIdx.x;
    if (t < 65536) hist[t] = 0u;
    if (t < 64)    ctrl[t] = 0u;
    if (t < 304)   keep[t] = -1;
    if (t < SORT_CAP) keys[t] = ~0ULL;
}

/* ---------------- weight transpose: w[512][9216] -> wt[9216][512] ---------------- */
__global__ __launch_bounds__(256) void k_wt(const float* __restrict__ w,
                                            float* __restrict__ wt) {
    __shared__ float T[64][65];
    const int k0  = blockIdx.x * 64;   /* 144 blocks */
    const int oc0 = blockIdx.y * 64;   /* 8 blocks   */
    const int c = threadIdx.x & 63;
    const int r = threadIdx.x >> 6;
#pragma unroll
    for (int i = 0; i < 16; ++i) {
        int rr = r + i * 4;
        T[rr][c] = w[(size_t)(oc0 + rr) * 9216 + k0 + c];
    }
    __syncthreads();
#pragma unroll
    for (int i = 0; i < 16; ++i) {
        int rr = r + i * 4;
        wt[(size_t)(k0 + rr) * 512 + oc0 + c] = T[c][rr];
    }
}

/* ---------------- conv 3x3, 1024->512, pad 1, relu ----------------
   grid (128 rows, 4 oc-tiles), 256 thr. Block: 128 oc x 128 px row.
   Thread: 8 oc x 8 px (64 acc). 8 input channels per K-chunk.
   X tile bank-swizzled; W pre-transposed -> clean f4 staging. */
__global__ __launch_bounds__(256) void k_conv3(const float* __restrict__ in,
                                               const float* __restrict__ wt,
                                               const float* __restrict__ bias,
                                               float* __restrict__ out) {
    const int y   = blockIdx.x;
    const int oc0 = blockIdx.y * 128;
    const int tid = threadIdx.x;
    const int og  = tid >> 4;   /* 0..15 -> oc = og*8 */
    const int pg  = tid & 15;   /* px = pg*8 */

    __shared__ __align__(16) float Xl[24 * 132];   /* [cp*3+dy][132 swizzled] 12.7KB */
    __shared__ __align__(16) float Wl[72 * 132];   /* [cp*9+r][oc 0..127]     38.0KB */

    /* one-time zero (halo cols + OOB rows stay zero forever) */
    for (int u = tid; u < 24 * 132; u += 256) Xl[u] = 0.f;

    const int q  = tid >> 5;   /* 0..7 */
    const int c4 = tid & 31;   /* float4 col-block */

    /* X staging precompute: slot i handles row q+8i, cols 4*c4+1..4*c4+4 */
    int xg[3], xa[3], xb[3];
    bool xok[3];
#pragma unroll
    for (int i = 0; i < 3; ++i) {
        int row = q + 8 * i;              /* cp*3+dy */
        int cp = row / 3, dy = row - cp * 3;
        int yy = y + dy - 1;
        xok[i] = (yy >= 0 && yy < HH);
        xg[i] = cp * NPIX + (xok[i] ? yy : 0) * WW + c4 * 4;
        xa[i] = row * 132 + swb(c4) * 4;       /* words +1..+3 */
        xb[i] = row * 132 + swb(c4 + 1) * 4;   /* word  +0     */
    }
    /* W staging: slot i -> row q+8i, oc-block c4 */
    const int wg0 = q * 512 + oc0 + c4 * 4;
    const int wl0 = q * 132 + c4 * 4;

    /* swizzled read offsets (thread-invariant) */
    const int xo0 = swb(2 * pg) * 4;
    const int xo1 = swb(2 * pg + 1) * 4;
    const int xo2 = swb(2 * pg + 2) * 4;
    const int wbase = og * 8;

    float acc[8][8];
#pragma unroll
    for (int o = 0; o < 8; ++o)
#pragma unroll
        for (int j = 0; j < 8; ++j) acc[o][j] = 0.f;

    const float* inp = in;
    const float* wtp = wt;
    __syncthreads();   /* zero-init visible */

    for (int cc = 0; cc < 128; ++cc) {
        float4 xf[3];
#pragma unroll
        for (int i = 0; i < 3; ++i)
            if (xok[i]) xf[i] = *(const float4*)(inp + xg[i]);
        float4 wf[9];
#pragma unroll
        for (int i = 0; i < 9; ++i)
            wf[i] = *(const float4*)(wtp + wg0 + i * 4096);
#pragma unroll
        for (int i = 0; i < 3; ++i)
            if (xok[i]) {
                Xl[xa[i] + 1] = xf[i].x;
                Xl[xa[i] + 2] = xf[i].y;
                Xl[xa[i] + 3] = xf[i].z;
                Xl[xb[i]]     = xf[i].w;
            }
#pragma unroll
        for (int i = 0; i < 9; ++i)
            *(float4*)&Wl[wl0 + i * 1056] = wf[i];
        __syncthreads();

#pragma unroll 1
        for (int cp = 0; cp < 8; ++cp) {
            float v[3][10];
#pragma unroll
            for (int dy = 0; dy < 3; ++dy) {
                const float* xp = &Xl[(cp * 3 + dy) * 132];
                float4 pa = *(const float4*)(xp + xo0);
                float4 pb = *(const float4*)(xp + xo1);
                float2 pc = *(const float2*)(xp + xo2);
                v[dy][0] = pa.x; v[dy][1] = pa.y; v[dy][2] = pa.z; v[dy][3] = pa.w;
                v[dy][4] = pb.x; v[dy][5] = pb.y; v[dy][6] = pb.z; v[dy][7] = pb.w;
                v[dy][8] = pc.x; v[dy][9] = pc.y;
            }
#pragma unroll
            for (int r = 0; r < 9; ++r) {
                const int dy = r / 3, dx = r % 3;
                const float* wp = &Wl[(cp * 9 + r) * 132 + wbase];
                const float4 w0 = *(const float4*)wp;
                const float4 w1 = *(const float4*)(wp + 4);
#pragma unroll
                for (int j = 0; j < 8; ++j) {
                    const float xv = v[dy][j + dx];
                    acc[0][j] = fmaf(w0.x, xv, acc[0][j]);
                    acc[1][j] = fmaf(w0.y, xv, acc[1][j]);
                    acc[2][j] = fmaf(w0.z, xv, acc[2][j]);
                    acc[3][j] = fmaf(w0.w, xv, acc[3][j]);
                    acc[4][j] = fmaf(w1.x, xv, acc[4][j]);
                    acc[5][j] = fmaf(w1.y, xv, acc[5][j]);
                    acc[6][j] = fmaf(w1.z, xv, acc[6][j]);
                    acc[7][j] = fmaf(w1.w, xv, acc[7][j]);
                }
            }
        }
        __syncthreads();
        inp += 8 * NPIX;
        wtp += 72 * 512;
    }
#pragma unroll
    for (int o = 0; o < 8; ++o) {
        const int oc = oc0 + og * 8 + o;
        const float b = bias[oc];
        float4 r0, r1;
        r0.x = fmaxf(acc[o][0] + b, 0.f);
        r0.y = fmaxf(acc[o][1] + b, 0.f);
        r0.z = fmaxf(acc[o][2] + b, 0.f);
        r0.w = fmaxf(acc[o][3] + b, 0.f);
        r1.x = fmaxf(acc[o][4] + b, 0.f);
        r1.y = fmaxf(acc[o][5] + b, 0.f);
        r1.z = fmaxf(acc[o][6] + b, 0.f);
        r1.w = fmaxf(acc[o][7] + b, 0.f);
        float* op = &out[(size_t)oc * NPIX + y * WW + pg * 8];
        *(float4*)op = r0;
        *(float4*)(op + 4) = r1;
    }
}

/* ---------------- fused 1x1 convs (cls 6 + bbox 24) + pair softmax ---------------- */
__global__ __launch_bounds__(256) void k_conv1(const float* __restrict__ conv1,
                                               const float* __restrict__ wcls,
                                               const float* __restrict__ bcls,
                                               const float* __restrict__ wbox,
                                               const float* __restrict__ bboxb,
                                               float* __restrict__ out) {
    const int tid = threadIdx.x;
    const int og = tid >> 4, pg = tid & 15;
    const int px0 = blockIdx.x * 64;
    __shared__ __align__(16) float Wl[32][32];
    __shared__ __align__(16) float Xl[32][64];
    __shared__ float Sc[6][64];

    float a0[4] = {0, 0, 0, 0}, a1[4] = {0, 0, 0, 0};

    for (int cc = 0; cc < 16; ++cc) {
        {
            int u = tid;
            int row = (u * 4) >> 5;
            int col = (u * 4) & 31;
            float4 v;
            if (row < 6)       v = *(const float4*)(wcls + row * 512 + cc * 32 + col);
            else if (row < 30) v = *(const float4*)(wbox + (row - 6) * 512 + cc * 32 + col);
            else               v = make_float4(0.f, 0.f, 0.f, 0.f);
            *(float4*)&Wl[row][col] = v;
        }
        for (int u = tid; u < 512; u += 256) {
            int row = (u * 4) >> 6, col = (u * 4) & 63;
            *(float4*)&Xl[row][col] =
                *(const float4*)(conv1 + (size_t)(cc * 32 + row) * NPIX + px0 + col);
        }
        __syncthreads();
#pragma unroll
        for (int cp = 0; cp < 32; ++cp) {
            const float4 x = *(const float4*)&Xl[cp][pg * 4];
            const float w0 = Wl[og][cp];
            const float w1 = Wl[og + 16][cp];
            a0[0] = fmaf(w0, x.x, a0[0]); a0[1] = fmaf(w0, x.y, a0[1]);
            a0[2] = fmaf(w0, x.z, a0[2]); a0[3] = fmaf(w0, x.w, a0[3]);
            a1[0] = fmaf(w1, x.x, a1[0]); a1[1] = fmaf(w1, x.y, a1[1]);
            a1[2] = fmaf(w1, x.z, a1[2]); a1[3] = fmaf(w1, x.w, a1[3]);
        }
        __syncthreads();
    }
    const int pxb = px0 + pg * 4;
    if (og < 6) {
        const float bc = bcls[og];
#pragma unroll
        for (int kk = 0; kk < 4; ++kk) Sc[og][pg * 4 + kk] = a0[kk] + bc;
    } else {
        const float bb = bboxb[og - 6];
#pragma unroll
        for (int kk = 0; kk < 4; ++kk)
            out[OUT_BBOX + (size_t)(og - 6) * NPIX + pxb + kk] = a0[kk] + bb;
    }
    if (og + 16 < 30) {
        const float bb = bboxb[og + 10];
#pragma unroll
        for (int kk = 0; kk < 4; ++kk)
            out[OUT_BBOX + (size_t)(og + 10) * NPIX + pxb + kk] = a1[kk] + bb;
    }
    __syncthreads();
    if (og < 6) {
        const int pa = og < 3 ? og + 3 : og - 3;
#pragma unroll
        for (int kk = 0; kk < 4; ++kk) {
            const float s = Sc[og][pg * 4 + kk], sp = Sc[pa][pg * 4 + kk];
            out[OUT_PROB + (size_t)og * NPIX + pxb + kk] = 1.0f / (1.0f + expf(sp - s));
        }
    }
}

/* ---------------- anchor decode + clip ---------------- */
__global__ void k_decode(const float* __restrict__ out, const float* __restrict__ meta,
                         float4* __restrict__ boxes, float* __restrict__ scores) {
#pragma clang fp contract(off)
    int t = blockIdx.x * blockDim.x + threadIdx.x;
    if (t >= NANCH) return;
    int a = t >> 14;
    int pix = t & 16383;
    int yc = pix >> 7, xc = pix & 127;
    int n = pix * 6 + a;
    float sc = out[OUT_PROB + (size_t)a * NPIX + pix];
    float d0 = out[OUT_BBOX + (size_t)(a * 4 + 0) * NPIX + pix];
    float d1 = out[OUT_BBOX + (size_t)(a * 4 + 1) * NPIX + pix];
    float d2 = out[OUT_BBOX + (size_t)(a * 4 + 2) * NPIX + pix];
    float d3 = out[OUT_BBOX + (size_t)(a * 4 + 3) * NPIX + pix];
    const float dims = (float)(16 << a);
    const float cxa = (xc + 0.5f) * 16.f;
    const float cya = (yc + 0.5f) * 16.f;
    float pcx = d0 * dims + cxa;
    float pcy = d1 * dims + cya;
    float pw  = expf(d2) * dims;
    float ph  = expf(d3) * dims;
    float imh = meta[0], imw = meta[1];
    float x1 = fminf(fmaxf(pcx - 0.5f * pw, 0.f), imw);
    float y1 = fminf(fmaxf(pcy - 0.5f * ph, 0.f), imh);
    float x2 = fminf(fmaxf(pcx + 0.5f * pw, 0.f), imw);
    float y2 = fminf(fmaxf(pcy + 0.5f * ph, 0.f), imh);
    boxes[n] = make_float4(x1, y1, x2, y2);
    scores[n] = sc;
}

/* ---------------- histogram on top-16 bits of score ---------------- */
__global__ void k_hist(const float* __restrict__ scores, u32* __restrict__ hist) {
    int t = blockIdx.x * blockDim.x + threadIdx.x;
    if (t >= NANCH) return;
    u32 b = __float_as_uint(scores[t]) >> 16;
    atomicAdd(&hist[b], 1u);
}

/* ---------------- find threshold bin (6000th largest) ---------------- */
__global__ void k_select(const u32* __restrict__ hist, u32* __restrict__ ctrl) {
    __shared__ u32 S[256];
    __shared__ u32 U[256];
    const int tid = threadIdx.x;
    u32 s = 0;
    for (int i = 0; i < 256; ++i) s += hist[tid * 256 + i];
    S[tid] = s;
    __syncthreads();
    if (tid == 0) {
        u32 acc = 0;
        for (int t = 255; t >= 0; --t) { U[t] = acc; acc += S[t]; }
    }
    __syncthreads();
    if (U[tid] < KPRE && U[tid] + S[tid] >= KPRE) {
        u32 acc = U[tid];
        for (int b = tid * 256 + 255; b >= tid * 256; --b) {
            u32 h = hist[b];
            if (acc + h >= KPRE) { ctrl[1] = (u32)b; ctrl[2] = acc; break; }
            acc += h;
        }
    }
}

/* ---------------- compact candidates ---------------- */
__global__ void k_compact(const float* __restrict__ scores, u32* __restrict__ ctrl,
                          u64* __restrict__ keys) {
    int t = blockIdx.x * blockDim.x + threadIdx.x;
    if (t >= NANCH) return;
    u32 bits = __float_as_uint(scores[t]);
    if ((bits >> 16) >= ctrl[1]) {
        u32 pos = atomicAdd(&ctrl[0], 1u);
        if (pos < SORT_CAP) keys[pos] = ((u64)(~bits) << 32) | (u32)t;
    }
}

/* ---------------- bitonic sort of 8192-key chunk in LDS ---------------- */
__global__ __launch_bounds__(1024) void k_sort_local(u64* __restrict__ keys) {
    __shared__ u64 lds[8192];
    const int tid = threadIdx.x;
    u64* g = keys + blockIdx.x * 8192;
    for (int u = tid; u < 8192; u += 1024) lds[u] = g[u];
    __syncthreads();
    for (int k = 2; k <= 8192; k <<= 1) {
        for (int j = k >> 1; j > 0; j >>= 1) {
            for (int u = tid; u < 4096; u += 1024) {
                int i = ((u & ~(j - 1)) << 1) | (u & (j - 1));
                int l = i | j;
                bool up = (i & k) == 0;
                u64 x = lds[i], y2 = lds[l];
                if ((x > y2) == up) { lds[i] = y2; lds[l] = x; }
            }
            __syncthreads();
        }
    }
    for (int u = tid; u < 8192; u += 1024) g[u] = lds[u];
}

/* ---------------- merge-path: first 6000 of two sorted 8192 runs ---------------- */
__global__ void k_merge(const u64* __restrict__ keys, u64* __restrict__ skeys) {
    int i = blockIdx.x * blockDim.x + threadIdx.x;
    if (i >= KPRE) return;
    const u64* A = keys;
    const u64* B = keys + 8192;
    int lo = i > 8192 ? i - 8192 : 0;
    int hi = i < 8192 ? i : 8192;
    while (lo < hi) {
        int a = (lo + hi) >> 1;
        if (A[a] < B[i - a - 1]) lo = a + 1; else hi = a;
    }
    int a = lo, b = i - lo;
    u64 va = (a < 8192) ? A[a] : ~0ULL;
    u64 vb = (b < 8192) ? B[b] : ~0ULL;
    skeys[i] = va < vb ? va : vb;
}

/* ---------------- gather top boxes + areas ---------------- */
__global__ void k_gather(const u64* __restrict__ skeys, const float4* __restrict__ boxes,
                         float4* __restrict__ tb, float* __restrict__ areas) {
#pragma clang fp contract(off)
    int i = blockIdx.x * blockDim.x + threadIdx.x;
    if (i >= KPRE) return;
    u32 n = (u32)(skeys[i] & 0xFFFFFFFFULL);
    float4 b = boxes[n];
    tb[i] = b;
    areas[i] = fmaxf(b.z - b.x, 0.f) * fmaxf(b.w - b.y, 0.f);
}

/* ---------------- suppression bitmap ---------------- */
__global__ __launch_bounds__(256) void k_bitmap(const float4* __restrict__ tb,
                                                const float* __restrict__ areas,
                                                u64* __restrict__ suppr) {
#pragma clang fp contract(off)
    const int i = blockIdx.x;
    const int lane = threadIdx.x & 63;
    const int wv = threadIdx.x >> 6;
    const float4 bi = tb[i];
    const float ai = areas[i];
    for (int Wd = wv; Wd < RW; Wd += 4) {
        int j = Wd * 64 + lane;
        bool sup = false;
        if (j < KPRE) {
            float4 bj = tb[j];
            float iw = fmaxf(fminf(bi.z, bj.z) - fmaxf(bi.x, bj.x), 0.f);
            float ih = fmaxf(fminf(bi.w, bj.w) - fmaxf(bi.y, bj.y), 0.f);
            float inter = iw * ih;
            float denom = ((areas[j] + ai) - inter) + 1e-9f;
            sup = (inter / denom) > NMS_T;
        }
        u64 m = __ballot(sup);
        if (lane == 0) suppr[(size_t)i * RW + Wd] = m;
    }
}

/* ---------------- greedy scan over bitmap ---------------- */
__global__ void k_scan(const u64* __restrict__ suppr, int* __restrict__ keep) {
    const int lane = threadIdx.x; /* 64 threads */
    u64 a0 = (lane < 93) ? ~0ULL : (lane == 93 ? ((1ULL << 48) - 1) : 0ULL);
    const int w1 = lane + 64;
    u64 a1 = (w1 < 93) ? ~0ULL : (w1 == 93 ? ((1ULL << 48) - 1) : 0ULL);
    int kept = 0;
    int i = 0;
    while (kept < KPOST) {
        int wi = i >> 6;
        if (wi >= 94) break;
        u64 wvv = (wi < 64) ? __shfl(a0, wi) : __shfl(a1, wi - 64);
        wvv &= (~0ULL) << (i & 63);
        if (wvv == 0ULL) { i = (wi + 1) << 6; continue; }
        int b = __ffsll((long long)wvv) - 1;
        i = (wi << 6) + b;
        if (lane == 0) keep[kept] = i;
        kept++;
        const u64* row = suppr + (size_t)i * RW;
        u64 s0 = row[lane];
        u64 s1 = (lane + 64 < RW) ? row[lane + 64] : 0ULL;
        a0 &= ~s0;
        a1 &= ~s1;
        i++;
    }
}

/* ---------------- write rois ---------------- */
__global__ void k_rois(const int* __restrict__ keep, const float4* __restrict__ tb,
                       float* __restrict__ out) {
    int r = blockIdx.x * blockDim.x + threadIdx.x;
    if (r >= KPOST) return;
    int k = keep[r];
    float4 b = make_float4(0.f, 0.f, 0.f, 0.f);
    if (k >= 0) b = tb[k];
    out[r * 5 + 0] = 0.f;
    out[r * 5 + 1] = b.x;
    out[r * 5 + 2] = b.y;
    out[r * 5 + 3] = b.z;
    out[r * 5 + 4] = b.w;
}

extern "C" void kernel_launch(void* const* d_in, const int* in_sizes, int n_in,
                              void* d_out, int out_size, void* d_ws, size_t ws_size,
                              hipStream_t stream) {
    (void)in_sizes; (void)n_in; (void)out_size; (void)ws_size;
    const float* x     = (const float*)d_in[0];
    const float* meta  = (const float*)d_in[1];
    const float* wc3   = (const float*)d_in[3];
    const float* bc3   = (const float*)d_in[4];
    const float* wcls  = (const float*)d_in[5];
    const float* bcls  = (const float*)d_in[6];
    const float* wbox  = (const float*)d_in[7];
    const float* bboxb = (const float*)d_in[8];
    float* out = (float*)d_out;
    char* ws = (char*)d_ws;

    float*  conv1  = (float*)(ws + WS_CONV1);
    float*  wt     = (float*)(ws + WS_WT);
    float4* boxes  = (float4*)(ws + WS_BOXES);
    float*  scores = (float*)(ws + WS_SCORE);
    u64*    keys   = (u64*)(ws + WS_KEYS);
    float4* tb     = (float4*)(ws + WS_TB);
    float*  areas  = (float*)(ws + WS_AREA);
    u64*    suppr  = (u64*)(ws + WS_SUP);
    u32*    hist   = (u32*)(ws + WS_HIST);
    u32*    ctrl   = (u32*)(ws + WS_CTRL);
    int*    keep   = (int*)(ws + WS_KEEP);
    u64*    skeys  = (u64*)(ws + WS_SKEYS);

    k_wt<<<dim3(144, 8), 256, 0, stream>>>(wc3, wt);
    k_conv3<<<dim3(128, 4), 256, 0, stream>>>(x, wt, bc3, conv1);
    k_init<<<256, 256, 0, stream>>>(hist, ctrl, keep, keys);   /* after conv3: aliases wt */
    k_conv1<<<256, 256, 0, stream>>>(conv1, wcls, bcls, wbox, bboxb, out);
    k_decode<<<384, 256, 0, stream>>>(out, meta, boxes, scores);
    k_hist<<<384, 256, 0, stream>>>(scores, hist);
    k_select<<<1, 256, 0, stream>>>(hist, ctrl);
    k_compact<<<384, 256, 0, stream>>>(scores, ctrl, keys);
    k_sort_local<<<2, 1024, 0, stream>>>(keys);
    k_merge<<<24, 256, 0, stream>>>(keys, skeys);
    k_gather<<<24, 256, 0, stream>>>(skeys, boxes, tb, areas);
    k_bitmap<<<6000, 256, 0, stream>>>(tb, areas, suppr);
    k_scan<<<1, 64, 0, stream>>>(suppr, keep);
    k_rois<<<2, 256, 0, stream>>>(keep, tb, out);
}